// Round 4
// baseline (440.251 us; speedup 1.0000x reference)
//
#include <hip/hip_runtime.h>
#include <stdint.h>

// MultiAttention fused kernel for MI355X (gfx950) — round 4
// B=131072 rows; D=105 (80 hm + 20 me + 5 tf); 10 attention groups.
// out  [B,105] fp32  (first 13,762,560 floats of d_out)
// alpha[B,1050] fp32 (next 137,625,600 floats of d_out)
//
// R4 (vs R3): no max-subtract (softmax shift-invariant; z bounded ~4);
// A-weights prescaled by log2(e) -> raw v_exp_f32; col-LUT read as ds_read_b64
// (7/group, hoisted); ctx gathers batched before exp math; A(g+1) prefetched
// during GEMM2; v_cvt_pk_bf16_f32 packing. Structure/occupancy unchanged.

#define NATT 10
#define DD   105
#define KP   136          // ctx k pitch in elements
#define RPB  128          // rows per block (4 waves x 32)
#define FRAG_PER_G (4*7)  // c x T fragments per group per operand
#define FRAG_ELEMS 512    // 64 lanes x 8 bf16
#define OP_ELEMS (NATT*FRAG_PER_G*FRAG_ELEMS)   // 143360 bf16 per operand pack

typedef __attribute__((ext_vector_type(8))) short short8v;  // 8 bf16 = MFMA A/B frag
typedef __attribute__((ext_vector_type(4))) float f4;
typedef float f4u __attribute__((ext_vector_type(4), aligned(4)));
typedef __attribute__((ext_vector_type(4))) unsigned int u32x4;
typedef __attribute__((ext_vector_type(2))) unsigned int u32x2;
typedef __attribute__((ext_vector_type(4))) unsigned short ushort4v;

__device__ __forceinline__ short f2bf(float x) {
  unsigned int u = __builtin_bit_cast(unsigned int, x);
  unsigned int r = (u + 0x7FFFu + ((u >> 16) & 1u)) >> 16;   // RNE
  return (short)(r & 0xFFFFu);
}
__device__ __forceinline__ float bf2f(int b) {
  unsigned int u = ((unsigned int)(b & 0xFFFF)) << 16;
  return __builtin_bit_cast(float, u);
}
__device__ __forceinline__ unsigned int pkbf(float lo, float hi) {
  unsigned int r;
  asm("v_cvt_pk_bf16_f32 %0, %1, %2" : "=v"(r) : "v"(lo), "v"(hi));
  return r;
}
__device__ __forceinline__ float exp2fast(float x) {
#if __has_builtin(__builtin_amdgcn_exp2f)
  return __builtin_amdgcn_exp2f(x);
#else
  return exp2f(x);
#endif
}

// ---------------- prep: build bf16 fragment packs in workspace ----------------
// Afrag[g][c][T][lane][j]: GEMM1 A-operand, PRESCALED by log2(e). Lane l elem j:
//   n = T*16+(l&15), k = c*32+(l>>4)*8+j
//   k<105:  A_w[(g*105+n)*105+k]*L2E      (0 if n>=105)
//   k==105: A_b[g*105+n]*L2E if n<105 else -1e30  (bias fold via ctx col105==1.0)
// Wfrag[g][cc][jt][lane][j]: GEMM2 B-operand, kappa2 k-slot map:
//   il = cc*32 + (l>>4)*4 + (j&3) + 16*(j>>2); jout = jt*16+(l&15)
//   il<105: block-diag [HM|ME|TF] weight at (jout, g*105+il)
//   il==105 && g==0: out-bias[jout]   (h slot forced to 1.0 at g==0)
// Lut [10][112] u16 (stride 112 -> 8B-aligned quads): col map for expanded idx
__global__ void prep_kernel(const float* __restrict__ Aw, const float* __restrict__ Ab,
                            const float* __restrict__ HMw, const float* __restrict__ HMb,
                            const float* __restrict__ MEw, const float* __restrict__ MEb,
                            const float* __restrict__ TFw, const float* __restrict__ TFb,
                            short* __restrict__ Afrag, short* __restrict__ Wfrag,
                            unsigned short* __restrict__ Lut)
{
  const float L2E = 1.4426950408889634f;
  int tid = blockIdx.x * blockDim.x + threadIdx.x;
  int NT  = gridDim.x * blockDim.x;

  for (int a = tid; a < OP_ELEMS; a += NT) {
    int j = a & 7, l = (a >> 3) & 63;
    int rem = a >> 9;            // g*28 + c*7 + T
    int T = rem % 7, rem2 = rem / 7;
    int c = rem2 & 3, g = rem2 >> 2;
    int n = T * 16 + (l & 15);
    int k = c * 32 + (l >> 4) * 8 + j;
    float v = 0.f;
    if (n < DD && k < DD) v = Aw[(g * DD + n) * DD + k] * L2E;
    else if (k == DD)     v = (n < DD) ? Ab[g * DD + n] * L2E : -1e30f;
    Afrag[a] = f2bf(v);
  }

  for (int a = tid; a < OP_ELEMS; a += NT) {
    int j = a & 7, l = (a >> 3) & 63;
    int rem = a >> 9;
    int jt = rem % 7, rem2 = rem / 7;
    int cc = rem2 & 3, g = rem2 >> 2;
    int jout = jt * 16 + (l & 15);
    int gg = l >> 4;
    int il = cc * 32 + gg * 4 + (j & 3) + ((j >> 2) << 4);
    float v = 0.f;
    if (il < DD && jout < DD) {
      int i = g * DD + il;
      if (i < 800)       { if (jout < 80)                v = HMw[jout * 800 + i]; }
      else if (i < 1000) { if (jout >= 80 && jout < 100) v = MEw[(jout - 80) * 200 + (i - 800)]; }
      else               { if (jout >= 100)              v = TFw[(jout - 100) * 50 + (i - 1000)]; }
    } else if (il == DD && g == 0 && jout < DD) {
      if (jout < 80)       v = HMb[jout];
      else if (jout < 100) v = MEb[jout - 80];
      else                 v = TFb[jout - 100];
    }
    Wfrag[a] = f2bf(v);
  }

  for (int a = tid; a < NATT * 112; a += NT) {
    int g = a / 112, n = a - (a / 112) * 112;
    int i = g * DD + n;
    int col;
    if (i < 800)       col = i % 80;
    else if (i < 1000) col = 80 + (i - 800) % 20;
    else if (i < 1050) col = 100 + (i - 1000) % 5;
    else               col = 100;  // alpha==0 there
    Lut[a] = (unsigned short)col;
  }
}

// ---------------- main fused kernel ----------------
// 1024 blocks x 256 threads; 4 waves x 32 rows; ZERO barriers.
// LDS: sCtx 128x136 bf16 (34816B) + sLut 1120 u16 (2240B) = 37056B.
__global__ __launch_bounds__(256, 2)
void fused_main(const float* __restrict__ hm, const float* __restrict__ me,
                const float* __restrict__ tf,
                const short* __restrict__ Afrag, const short* __restrict__ Wfrag,
                const unsigned short* __restrict__ Lut,
                float* __restrict__ out, float* __restrict__ alphaOut)
{
  __shared__ short sCtx[RPB * KP];
  __shared__ unsigned short sLut[NATT * 112];

  const int tid  = threadIdx.x;
  const int lane = tid & 63;
  const int wave = tid >> 6;
  const int l15  = lane & 15;
  const int g16  = lane >> 4;
  const long rowbase = (long)blockIdx.x * RPB;
  const int wrow0 = wave * 32;     // this wave's first local row

  // ---- wave-private ctx staging (rows wrow0..wrow0+31 only) ----
  for (int q = lane; q < 32 * 20; q += 64) {        // hm: 20 f4 per row
    int r = q / 20, c = q - r * 20;
    f4 v = *(const f4*)(hm + (rowbase + wrow0 + r) * 80 + c * 4);
    u32x2 b; b[0] = pkbf(v[0], v[1]); b[1] = pkbf(v[2], v[3]);
    *(u32x2*)&sCtx[(wrow0 + r) * KP + c * 4] = b;
  }
  for (int q = lane; q < 32 * 5; q += 64) {         // me: 5 f4 per row
    int r = q / 5, c = q - r * 5;
    f4 v = *(const f4*)(me + (rowbase + wrow0 + r) * 20 + c * 4);
    u32x2 b; b[0] = pkbf(v[0], v[1]); b[1] = pkbf(v[2], v[3]);
    *(u32x2*)&sCtx[(wrow0 + r) * KP + 80 + c * 4] = b;
  }
  for (int q = lane; q < 32 * 5; q += 64) {         // tf: 5 scalars per row
    int r = q / 5, c = q - r * 5;
    sCtx[(wrow0 + r) * KP + 100 + c] = f2bf(tf[(rowbase + wrow0 + r) * 5 + c]);
  }
  for (int q = lane; q < 32 * 31; q += 64) {        // pad cols 105..135; col105 = 1.0
    int r = q / 31, c = q - r * 31;
    sCtx[(wrow0 + r) * KP + 105 + c] = (c == 0) ? (short)0x3F80 : (short)0;
  }
  for (int q = lane; q < NATT * 112; q += 64) sLut[q] = Lut[q];  // redundant identical

  // ---- preload ctx MFMA fragments (group-invariant) ----
  short8v cf0[4], cf1[4];
  #pragma unroll
  for (int c = 0; c < 4; ++c) {
    cf0[c] = *(const short8v*)&sCtx[(wrow0 +      l15) * KP + c * 32 + g16 * 8];
    cf1[c] = *(const short8v*)&sCtx[(wrow0 + 16 + l15) * KP + c * 32 + g16 * 8];
  }

  f4 acc2[2][7];
  #pragma unroll
  for (int rt = 0; rt < 2; ++rt)
    #pragma unroll
    for (int jt = 0; jt < 7; ++jt) {
      acc2[rt][jt][0]=0.f; acc2[rt][jt][1]=0.f; acc2[rt][jt][2]=0.f; acc2[rt][jt][3]=0.f;
    }

  const short* Afl = Afrag + lane * 8;
  const short* Wfl = Wfrag + lane * 8;

  short8v afp[7];   // cross-group A prefetch (c=0 of g+1)

  for (int g = 0; g < NATT; ++g) {
    const short* Ag = Afl + g * FRAG_PER_G * FRAG_ELEMS;
    const short* Wg = Wfl + g * FRAG_PER_G * FRAG_ELEMS;

    // ---- hoist col-LUT quads for this group (7 x ds_read_b64) ----
    ushort4v cols[7];
    #pragma unroll
    for (int T = 0; T < 7; ++T)
      cols[T] = *(const ushort4v*)&sLut[g * 112 + T * 16 + g16 * 4];

    // ---- GEMM1 (swapped): z tile D[n][r], n=16T+4*g16+reg, r=l15 ----
    f4 za[2][7];
    #pragma unroll
    for (int rt = 0; rt < 2; ++rt)
      #pragma unroll
      for (int T = 0; T < 7; ++T) { za[rt][T][0]=0.f; za[rt][T][1]=0.f; za[rt][T][2]=0.f; za[rt][T][3]=0.f; }

    short8v afc[7], afn[7];
    if (g == 0) {
      #pragma unroll
      for (int T = 0; T < 7; ++T) afc[T] = *(const short8v*)(Ag + T * FRAG_ELEMS);
    } else {
      #pragma unroll
      for (int T = 0; T < 7; ++T) afc[T] = afp[T];   // prefetched during prior GEMM2
    }
    #pragma unroll
    for (int c = 0; c < 4; ++c) {
      if (c < 3) {
        #pragma unroll
        for (int T = 0; T < 7; ++T) afn[T] = *(const short8v*)(Ag + ((c + 1) * 7 + T) * FRAG_ELEMS);
      }
      #pragma unroll
      for (int T = 0; T < 7; ++T) {
        za[0][T] = __builtin_amdgcn_mfma_f32_16x16x32_bf16(afc[T], cf0[c], za[0][T], 0, 0, 0);
        za[1][T] = __builtin_amdgcn_mfma_f32_16x16x32_bf16(afc[T], cf1[c], za[1][T], 0, 0, 0);
      }
      if (c < 3) {
        #pragma unroll
        for (int T = 0; T < 7; ++T) afc[T] = afn[T];
      }
    }

    // ---- prefetch GEMM2 cc=0 B-frags (hide under softmax) ----
    short8v wfc[7], wfn[7];
    #pragma unroll
    for (int T = 0; T < 7; ++T) wfc[T] = *(const short8v*)(Wg + T * FRAG_ELEMS);

    // ---- softmax (no max-subtract; exp2 of prescaled z) + alpha + h build ----
    u32x4 hfu[2][4];
    #pragma unroll
    for (int rt = 0; rt < 2; ++rt) {
      const int rowl = wrow0 + rt * 16 + l15;
      const short* crow = &sCtx[rowl * KP];

      // batched gathers, issued before the exp/sum math (latency overlap)
      short eb[28];
      #pragma unroll
      for (int T = 0; T < 7; ++T)
        #pragma unroll
        for (int k = 0; k < 4; ++k) eb[T * 4 + k] = crow[cols[T][k]];

      float s = 0.f;
      #pragma unroll
      for (int T = 0; T < 7; ++T)
        #pragma unroll
        for (int k = 0; k < 4; ++k) {
          float p = exp2fast(za[rt][T][k]);   // pad cols: z=-1e30 -> 0
          za[rt][T][k] = p;
          s += p;
        }
      s += __shfl_xor(s, 16);
      s += __shfl_xor(s, 32);
      float inv = __fdividef(1.f, s);

      float* arow = alphaOut + (rowbase + rowl) * 1050 + g * DD;

      #pragma unroll
      for (int T = 0; T < 7; ++T) {
        f4 av = za[rt][T] * inv;
        int n0 = T * 16 + g16 * 4;
        if (T < 6) {
          *(f4u*)(arow + n0) = av;               // dwordx4
        } else {
          if (g16 < 2)       *(f4u*)(arow + n0) = av;
          else if (g16 == 2) arow[104] = av[0];  // n=104 only; n>=105 masked
        }
        float h0 = av[0] * bf2f(eb[T * 4 + 0]);
        float h1 = av[1] * bf2f(eb[T * 4 + 1]);
        float h2 = av[2] * bf2f(eb[T * 4 + 2]);
        float h3 = av[3] * bf2f(eb[T * 4 + 3]);
        hfu[rt][T >> 1][(T & 1) * 2 + 0] = pkbf(h0, h1);
        hfu[rt][T >> 1][(T & 1) * 2 + 1] = pkbf(h2, h3);
      }
      hfu[rt][3][2] = 0u; hfu[rt][3][3] = 0u;    // T=7 half (k-slots unused)
    }
    if (g == 0 && g16 == 2) {      // il=105 slot := 1.0 -> GEMM2 adds out-bias once
      hfu[0][3][0] = (hfu[0][3][0] & 0xFFFFu) | 0x3F800000u;
      hfu[1][3][0] = (hfu[1][3][0] & 0xFFFFu) | 0x3F800000u;
    }

    // ---- GEMM2 accumulate (2-stage pipeline) + A(g+1) prefetch ----
    #pragma unroll
    for (int cc = 0; cc < 4; ++cc) {
      if (cc < 3) {
        #pragma unroll
        for (int T = 0; T < 7; ++T) wfn[T] = *(const short8v*)(Wg + ((cc + 1) * 7 + T) * FRAG_ELEMS);
      }
      if (cc == 0 && g < NATT - 1) {
        #pragma unroll
        for (int T = 0; T < 7; ++T) afp[T] = *(const short8v*)(Ag + FRAG_PER_G * FRAG_ELEMS + T * FRAG_ELEMS);
      }
      short8v ha0 = __builtin_bit_cast(short8v, hfu[0][cc]);
      short8v ha1 = __builtin_bit_cast(short8v, hfu[1][cc]);
      #pragma unroll
      for (int jt = 0; jt < 7; ++jt) {
        acc2[0][jt] = __builtin_amdgcn_mfma_f32_16x16x32_bf16(ha0, wfc[jt], acc2[0][jt], 0, 0, 0);
        acc2[1][jt] = __builtin_amdgcn_mfma_f32_16x16x32_bf16(ha1, wfc[jt], acc2[1][jt], 0, 0, 0);
      }
      if (cc < 3) {
        #pragma unroll
        for (int T = 0; T < 7; ++T) wfc[T] = wfn[T];
      }
    }
  }

  // ---- epilogue: bias already in acc2; D2[r][j]: r=rt*16+4*g16+k, j=16*jt+l15 ----
  #pragma unroll
  for (int jt = 0; jt < 7; ++jt) {
    int j = jt * 16 + l15;
    if (j < DD) {
      #pragma unroll
      for (int rt = 0; rt < 2; ++rt)
        #pragma unroll
        for (int k = 0; k < 4; ++k) {
          long row = rowbase + wrow0 + rt * 16 + g16 * 4 + k;
          out[row * DD + j] = acc2[rt][jt][k];
        }
    }
  }
}

// ---------------- launch ----------------
extern "C" void kernel_launch(void* const* d_in, const int* in_sizes, int n_in,
                              void* d_out, int out_size, void* d_ws, size_t ws_size,
                              hipStream_t stream)
{
  const float* hm  = (const float*)d_in[0];
  const float* me  = (const float*)d_in[1];
  const float* tf  = (const float*)d_in[2];
  const float* Aw  = (const float*)d_in[3];
  const float* Ab  = (const float*)d_in[4];
  const float* HMw = (const float*)d_in[5];
  const float* HMb = (const float*)d_in[6];
  const float* MEw = (const float*)d_in[7];
  const float* MEb = (const float*)d_in[8];
  const float* TFw = (const float*)d_in[9];
  const float* TFb = (const float*)d_in[10];

  char* ws = (char*)d_ws;
  short* Afrag = (short*)(ws + 0);                 // 286720 B
  short* Wfrag = (short*)(ws + 286720);            // 286720 B
  unsigned short* Lut = (unsigned short*)(ws + 573440); // 2240 B (total 575680)

  float* outP     = (float*)d_out;
  float* alphaOut = outP + (long)131072 * DD;

  prep_kernel<<<320, 256, 0, stream>>>(Aw, Ab, HMw, HMb, MEw, MEb, TFw, TFb,
                                       Afrag, Wfrag, Lut);
  fused_main<<<1024, 256, 0, stream>>>(hm, me, tf, Afrag, Wfrag, Lut,
                                       outP, alphaOut);
}

// Round 5
// 341.471 us; speedup vs baseline: 1.2893x; 1.2893x over previous
//
#include <hip/hip_runtime.h>
#include <stdint.h>

// MultiAttention fused kernel for MI355X (gfx950) — round 5
// B=131072 rows; D=105 (80 hm + 20 me + 5 tf); 10 attention groups.
// out  [B,105] fp32  (first 13,762,560 floats of d_out)
// alpha[B,1050] fp32 (next 137,625,600 floats of d_out)
//
// R5: register-lean redesign. 16 rows/wave (RPB=64), single row-tile ->
// peak live state ~95 VGPR -> fits the 128-reg/4-wave occupancy step with no
// spill (R2/R4 both died on spills). Zero barriers, no explicit prefetch
// buffers (TLP at 16 waves/CU hides L2 latency). launch_bounds(256,4).

#define NATT 10
#define DD   105
#define KP   136          // ctx k pitch in elements
#define RPB  64           // rows per block (4 waves x 16)
#define FRAG_PER_G (4*7)  // c x T fragments per group per operand
#define FRAG_ELEMS 512    // 64 lanes x 8 bf16
#define OP_ELEMS (NATT*FRAG_PER_G*FRAG_ELEMS)   // 143360 bf16 per operand pack

typedef __attribute__((ext_vector_type(8))) short short8v;  // 8 bf16 = MFMA A/B frag
typedef __attribute__((ext_vector_type(4))) float f4;
typedef float f4u __attribute__((ext_vector_type(4), aligned(4)));
typedef __attribute__((ext_vector_type(4))) unsigned int u32x4;
typedef __attribute__((ext_vector_type(2))) unsigned int u32x2;
typedef __attribute__((ext_vector_type(4))) unsigned short ushort4v;

__device__ __forceinline__ short f2bf(float x) {
  unsigned int u = __builtin_bit_cast(unsigned int, x);
  unsigned int r = (u + 0x7FFFu + ((u >> 16) & 1u)) >> 16;   // RNE
  return (short)(r & 0xFFFFu);
}
__device__ __forceinline__ float bf2f(int b) {
  unsigned int u = ((unsigned int)(b & 0xFFFF)) << 16;
  return __builtin_bit_cast(float, u);
}
__device__ __forceinline__ unsigned int pkbf(float lo, float hi) {
  unsigned int r;
  asm("v_cvt_pk_bf16_f32 %0, %1, %2" : "=v"(r) : "v"(lo), "v"(hi));
  return r;
}
__device__ __forceinline__ float exp2fast(float x) {
  return exp2f(x);     // maps to v_exp_f32 on gfx950
}

// ---------------- prep: build bf16 fragment packs in workspace ----------------
// Afrag[g][c][T][lane][j]: GEMM1 A-operand, PRESCALED by log2(e). Lane l elem j:
//   n = T*16+(l&15), k = c*32+(l>>4)*8+j
//   k<105:  A_w[(g*105+n)*105+k]*L2E      (0 if n>=105)
//   k==105: A_b[g*105+n]*L2E if n<105 else -1e30  (bias fold via ctx col105==1.0)
// Wfrag[g][cc][jt][lane][j]: GEMM2 B-operand, kappa2 k-slot map:
//   il = cc*32 + (l>>4)*4 + (j&3) + 16*(j>>2); jout = jt*16+(l&15)
//   il<105: block-diag [HM|ME|TF] weight at (jout, g*105+il)
//   il==105 && g==0: out-bias[jout]   (h slot forced to 1.0 at g==0)
// Lut [10][112] u16 (8B-aligned quads): expanded-col -> ctx-col map
__global__ void prep_kernel(const float* __restrict__ Aw, const float* __restrict__ Ab,
                            const float* __restrict__ HMw, const float* __restrict__ HMb,
                            const float* __restrict__ MEw, const float* __restrict__ MEb,
                            const float* __restrict__ TFw, const float* __restrict__ TFb,
                            short* __restrict__ Afrag, short* __restrict__ Wfrag,
                            unsigned short* __restrict__ Lut)
{
  const float L2E = 1.4426950408889634f;
  int tid = blockIdx.x * blockDim.x + threadIdx.x;
  int NT  = gridDim.x * blockDim.x;

  for (int a = tid; a < OP_ELEMS; a += NT) {
    int j = a & 7, l = (a >> 3) & 63;
    int rem = a >> 9;            // g*28 + c*7 + T
    int T = rem % 7, rem2 = rem / 7;
    int c = rem2 & 3, g = rem2 >> 2;
    int n = T * 16 + (l & 15);
    int k = c * 32 + (l >> 4) * 8 + j;
    float v = 0.f;
    if (n < DD && k < DD) v = Aw[(g * DD + n) * DD + k] * L2E;
    else if (k == DD)     v = (n < DD) ? Ab[g * DD + n] * L2E : -1e30f;
    Afrag[a] = f2bf(v);
  }

  for (int a = tid; a < OP_ELEMS; a += NT) {
    int j = a & 7, l = (a >> 3) & 63;
    int rem = a >> 9;
    int jt = rem % 7, rem2 = rem / 7;
    int cc = rem2 & 3, g = rem2 >> 2;
    int jout = jt * 16 + (l & 15);
    int gg = l >> 4;
    int il = cc * 32 + gg * 4 + (j & 3) + ((j >> 2) << 4);
    float v = 0.f;
    if (il < DD && jout < DD) {
      int i = g * DD + il;
      if (i < 800)       { if (jout < 80)                v = HMw[jout * 800 + i]; }
      else if (i < 1000) { if (jout >= 80 && jout < 100) v = MEw[(jout - 80) * 200 + (i - 800)]; }
      else               { if (jout >= 100)              v = TFw[(jout - 100) * 50 + (i - 1000)]; }
    } else if (il == DD && g == 0 && jout < DD) {
      if (jout < 80)       v = HMb[jout];
      else if (jout < 100) v = MEb[jout - 80];
      else                 v = TFb[jout - 100];
    }
    Wfrag[a] = f2bf(v);
  }

  for (int a = tid; a < NATT * 112; a += NT) {
    int g = a / 112, n = a - (a / 112) * 112;
    int i = g * DD + n;
    int col;
    if (i < 800)       col = i % 80;
    else if (i < 1000) col = 80 + (i - 800) % 20;
    else if (i < 1050) col = 100 + (i - 1000) % 5;
    else               col = 100;  // alpha==0 there
    Lut[a] = (unsigned short)col;
  }
}

// ---------------- main fused kernel ----------------
// 2048 blocks x 256 threads; 4 waves x 16 rows; ZERO barriers.
// LDS: sCtx 64x136 bf16 (17408B) + sLut 1120 u16 (2240B) = 19648B.
__global__ __launch_bounds__(256, 4)
void fused_main(const float* __restrict__ hm, const float* __restrict__ me,
                const float* __restrict__ tf,
                const short* __restrict__ Afrag, const short* __restrict__ Wfrag,
                const unsigned short* __restrict__ Lut,
                float* __restrict__ out, float* __restrict__ alphaOut)
{
  __shared__ short sCtx[RPB * KP];
  __shared__ unsigned short sLut[NATT * 112];

  const int tid  = threadIdx.x;
  const int lane = tid & 63;
  const int wave = tid >> 6;
  const int l15  = lane & 15;
  const int g16  = lane >> 4;
  const long rowbase = (long)blockIdx.x * RPB;
  const int wrow0 = wave * 16;     // this wave's first local row

  // ---- wave-private ctx staging (rows wrow0..wrow0+15 only) ----
  for (int q = lane; q < 16 * 20; q += 64) {        // hm: 20 f4 per row
    int r = q / 20, c = q - r * 20;
    f4 v = *(const f4*)(hm + (rowbase + wrow0 + r) * 80 + c * 4);
    u32x2 b; b[0] = pkbf(v[0], v[1]); b[1] = pkbf(v[2], v[3]);
    *(u32x2*)&sCtx[(wrow0 + r) * KP + c * 4] = b;
  }
  for (int q = lane; q < 16 * 5; q += 64) {         // me: 5 f4 per row
    int r = q / 5, c = q - r * 5;
    f4 v = *(const f4*)(me + (rowbase + wrow0 + r) * 20 + c * 4);
    u32x2 b; b[0] = pkbf(v[0], v[1]); b[1] = pkbf(v[2], v[3]);
    *(u32x2*)&sCtx[(wrow0 + r) * KP + 80 + c * 4] = b;
  }
  for (int q = lane; q < 16 * 5; q += 64) {         // tf: 5 scalars per row
    int r = q / 5, c = q - r * 5;
    sCtx[(wrow0 + r) * KP + 100 + c] = f2bf(tf[(rowbase + wrow0 + r) * 5 + c]);
  }
  for (int q = lane; q < 16 * 31; q += 64) {        // pad cols 105..135; col105 = 1.0
    int r = q / 31, c = q - r * 31;
    sCtx[(wrow0 + r) * KP + 105 + c] = (c == 0) ? (short)0x3F80 : (short)0;
  }
  for (int q = lane; q < NATT * 112; q += 64) sLut[q] = Lut[q];  // redundant identical

  f4 acc2[7];
  #pragma unroll
  for (int jt = 0; jt < 7; ++jt) {
    acc2[jt][0]=0.f; acc2[jt][1]=0.f; acc2[jt][2]=0.f; acc2[jt][3]=0.f;
  }

  for (int g = 0; g < NATT; ++g) {
    const short* Ag = Afrag + (g * FRAG_PER_G) * FRAG_ELEMS + lane * 8;
    const short* Wg = Wfrag + (g * FRAG_PER_G) * FRAG_ELEMS + lane * 8;

    // ---- GEMM1 (swapped): z tile D[n][r], n=16T+4*g16+reg, r=l15 ----
    f4 za[7];
    #pragma unroll
    for (int T = 0; T < 7; ++T) { za[T][0]=0.f; za[T][1]=0.f; za[T][2]=0.f; za[T][3]=0.f; }

    #pragma unroll
    for (int c = 0; c < 4; ++c) {
      short8v cf = *(const short8v*)&sCtx[(wrow0 + l15) * KP + c * 32 + g16 * 8];
      #pragma unroll
      for (int T = 0; T < 7; ++T) {
        short8v af = *(const short8v*)(Ag + (c * 7 + T) * FRAG_ELEMS);
        za[T] = __builtin_amdgcn_mfma_f32_16x16x32_bf16(af, cf, za[T], 0, 0, 0);
      }
    }

    // ---- col-LUT quads for this group (7 x ds_read_b64) ----
    ushort4v cols[7];
    #pragma unroll
    for (int T = 0; T < 7; ++T)
      cols[T] = *(const ushort4v*)&sLut[g * 112 + T * 16 + g16 * 4];

    // ---- softmax (no max-subtract; exp2 of prescaled z) ----
    float s = 0.f;
    #pragma unroll
    for (int T = 0; T < 7; ++T)
      #pragma unroll
      for (int k = 0; k < 4; ++k) {
        float p = exp2fast(za[T][k]);   // pad cols: z=-1e30 -> 0
        za[T][k] = p;
        s += p;
      }
    s += __shfl_xor(s, 16);
    s += __shfl_xor(s, 32);
    float inv = __fdividef(1.f, s);

    const int rowl = wrow0 + l15;
    float* arow = alphaOut + (rowbase + rowl) * 1050 + g * DD;
    const short* crow = &sCtx[rowl * KP];

    // ---- alpha store + h build ----
    u32x4 hfu[4];
    #pragma unroll
    for (int T = 0; T < 7; ++T) {
      f4 av = za[T] * inv;
      int n0 = T * 16 + g16 * 4;
      if (T < 6) {
        *(f4u*)(arow + n0) = av;               // dwordx4
      } else {
        if (g16 < 2)       *(f4u*)(arow + n0) = av;
        else if (g16 == 2) arow[104] = av[0];  // n=104 only; n>=105 masked
      }
      float h0 = av[0] * bf2f(crow[cols[T][0]]);
      float h1 = av[1] * bf2f(crow[cols[T][1]]);
      float h2 = av[2] * bf2f(crow[cols[T][2]]);
      float h3 = av[3] * bf2f(crow[cols[T][3]]);
      hfu[T >> 1][(T & 1) * 2 + 0] = pkbf(h0, h1);
      hfu[T >> 1][(T & 1) * 2 + 1] = pkbf(h2, h3);
    }
    hfu[3][2] = 0u; hfu[3][3] = 0u;            // T=7 half (k-slots unused)
    if (g == 0 && g16 == 2) {                  // il=105 slot := 1.0 -> out-bias once
      hfu[3][0] = (hfu[3][0] & 0xFFFFu) | 0x3F800000u;
    }

    // ---- GEMM2 accumulate: out[r][j] += sum_il h[r][105g+il] * Wall[j][105g+il] ----
    #pragma unroll
    for (int cc = 0; cc < 4; ++cc) {
      short8v ha = __builtin_bit_cast(short8v, hfu[cc]);
      #pragma unroll
      for (int jt = 0; jt < 7; ++jt) {
        short8v wf = *(const short8v*)(Wg + (cc * 7 + jt) * FRAG_ELEMS);
        acc2[jt] = __builtin_amdgcn_mfma_f32_16x16x32_bf16(ha, wf, acc2[jt], 0, 0, 0);
      }
    }
  }

  // ---- epilogue: bias already in acc2; D2[r][j]: r=g16*4+k, j=16*jt+l15 ----
  #pragma unroll
  for (int jt = 0; jt < 7; ++jt) {
    int j = jt * 16 + l15;
    if (j < DD) {
      #pragma unroll
      for (int k = 0; k < 4; ++k) {
        long row = rowbase + wrow0 + g16 * 4 + k;
        out[row * DD + j] = acc2[jt][k];
      }
    }
  }
}

// ---------------- launch ----------------
extern "C" void kernel_launch(void* const* d_in, const int* in_sizes, int n_in,
                              void* d_out, int out_size, void* d_ws, size_t ws_size,
                              hipStream_t stream)
{
  const float* hm  = (const float*)d_in[0];
  const float* me  = (const float*)d_in[1];
  const float* tf  = (const float*)d_in[2];
  const float* Aw  = (const float*)d_in[3];
  const float* Ab  = (const float*)d_in[4];
  const float* HMw = (const float*)d_in[5];
  const float* HMb = (const float*)d_in[6];
  const float* MEw = (const float*)d_in[7];
  const float* MEb = (const float*)d_in[8];
  const float* TFw = (const float*)d_in[9];
  const float* TFb = (const float*)d_in[10];

  char* ws = (char*)d_ws;
  short* Afrag = (short*)(ws + 0);                 // 286720 B
  short* Wfrag = (short*)(ws + 286720);            // 286720 B
  unsigned short* Lut = (unsigned short*)(ws + 573440); // 2240 B (total 575680)

  float* outP     = (float*)d_out;
  float* alphaOut = outP + (long)131072 * DD;

  prep_kernel<<<320, 256, 0, stream>>>(Aw, Ab, HMw, HMb, MEw, MEb, TFw, TFb,
                                       Afrag, Wfrag, Lut);
  fused_main<<<2048, 256, 0, stream>>>(hm, me, tf, Afrag, Wfrag, Lut,
                                       outP, alphaOut);
}

// Round 6
// 290.372 us; speedup vs baseline: 1.5162x; 1.1760x over previous
//
#include <hip/hip_runtime.h>
#include <stdint.h>

// MultiAttention fused kernel for MI355X (gfx950) — round 6
// B=131072 rows; D=105 (80 hm + 20 me + 5 tf); 10 attention groups.
// out  [B,105] fp32  (first 13,762,560 floats of d_out)
// alpha[B,1050] fp32 (next 137,625,600 floats of d_out)
//
// R6 (vs R3 @307us): GEMM1 A-fragments staged into block-shared LDS via
// global_load_lds (async, zero VGPR), single-buffered, prefetched one group
// ahead under softmax+GEMM2. A-traffic /4 and A-latency hidden; GEMM1 reads
// become contiguous ds_read_b128. W keeps the register 2-stage pipeline.
// 2 barriers/group (their implicit vmcnt(0) drain fences global_load_lds).
// KP 136->112, u8 LUT quads, exp2-prescaled A (no max-subtract), pkbf.

#define NATT 10
#define DD   105
#define KP   112          // ctx k pitch (cols 0..104 real, 105=1.0 bias, 106..111=0)
#define RPB  128          // rows per block (4 waves x 32)
#define FRAG_PER_G 28     // c(4) x T(7) fragments per group per operand
#define FRAG_ELEMS 512    // 64 lanes x 8 bf16 (1KB)
#define OP_ELEMS (NATT*FRAG_PER_G*FRAG_ELEMS)

typedef __attribute__((ext_vector_type(8))) short short8v;  // 8 bf16 = MFMA A/B frag
typedef __attribute__((ext_vector_type(4))) float f4;
typedef float f4u __attribute__((ext_vector_type(4), aligned(4)));
typedef __attribute__((ext_vector_type(4))) unsigned int u32x4;
typedef __attribute__((ext_vector_type(2))) unsigned int u32x2;

__device__ __forceinline__ short f2bf(float x) {
  unsigned int u = __builtin_bit_cast(unsigned int, x);
  unsigned int r = (u + 0x7FFFu + ((u >> 16) & 1u)) >> 16;   // RNE
  return (short)(r & 0xFFFFu);
}
__device__ __forceinline__ float bf2f(int b) {
  unsigned int u = ((unsigned int)(b & 0xFFFF)) << 16;
  return __builtin_bit_cast(float, u);
}
__device__ __forceinline__ unsigned int pkbf(float lo, float hi) {
  unsigned int r;
  asm("v_cvt_pk_bf16_f32 %0, %1, %2" : "=v"(r) : "v"(lo), "v"(hi));
  return r;
}
// async global(16B/lane) -> LDS(base + lane*16); fenced by __syncthreads' drain
__device__ __forceinline__ void gload_lds16(const void* g, void* l) {
  __builtin_amdgcn_global_load_lds(
      (const __attribute__((address_space(1))) unsigned int*)g,
      (__attribute__((address_space(3))) unsigned int*)l, 16, 0, 0);
}

// ---------------- prep: build bf16 fragment packs in workspace ----------------
// Afrag[g][c][T][lane][j]: GEMM1 A-operand, PRESCALED by log2(e).
//   n = T*16+(l&15), k = c*32+(l>>4)*8+j
//   k<105: A_w[(g*105+n)*105+k]*L2E (0 if n>=105); k==105: A_b*L2E or -1e30 pad
// Wfrag[g][cc][jt][lane][j]: GEMM2 B-operand, kappa2 k-slot map:
//   il = cc*32 + (l>>4)*4 + (j&3) + 16*(j>>2); jout = jt*16+(l&15)
//   il<105: block-diag [HM|ME|TF] weight; il==105 && g==0: out-bias[jout]
// Lut8 [10][112] u8: expanded-col -> ctx-col map
__global__ void prep_kernel(const float* __restrict__ Aw, const float* __restrict__ Ab,
                            const float* __restrict__ HMw, const float* __restrict__ HMb,
                            const float* __restrict__ MEw, const float* __restrict__ MEb,
                            const float* __restrict__ TFw, const float* __restrict__ TFb,
                            short* __restrict__ Afrag, short* __restrict__ Wfrag,
                            unsigned char* __restrict__ Lut8)
{
  const float L2E = 1.4426950408889634f;
  int tid = blockIdx.x * blockDim.x + threadIdx.x;
  int NT  = gridDim.x * blockDim.x;

  for (int a = tid; a < OP_ELEMS; a += NT) {
    int j = a & 7, l = (a >> 3) & 63;
    int rem = a >> 9;            // g*28 + c*7 + T
    int T = rem % 7, rem2 = rem / 7;
    int c = rem2 & 3, g = rem2 >> 2;
    int n = T * 16 + (l & 15);
    int k = c * 32 + (l >> 4) * 8 + j;
    float v = 0.f;
    if (n < DD && k < DD) v = Aw[(g * DD + n) * DD + k] * L2E;
    else if (k == DD)     v = (n < DD) ? Ab[g * DD + n] * L2E : -1e30f;
    Afrag[a] = f2bf(v);
  }

  for (int a = tid; a < OP_ELEMS; a += NT) {
    int j = a & 7, l = (a >> 3) & 63;
    int rem = a >> 9;
    int jt = rem % 7, rem2 = rem / 7;
    int cc = rem2 & 3, g = rem2 >> 2;
    int jout = jt * 16 + (l & 15);
    int gg = l >> 4;
    int il = cc * 32 + gg * 4 + (j & 3) + ((j >> 2) << 4);
    float v = 0.f;
    if (il < DD && jout < DD) {
      int i = g * DD + il;
      if (i < 800)       { if (jout < 80)                v = HMw[jout * 800 + i]; }
      else if (i < 1000) { if (jout >= 80 && jout < 100) v = MEw[(jout - 80) * 200 + (i - 800)]; }
      else               { if (jout >= 100)              v = TFw[(jout - 100) * 50 + (i - 1000)]; }
    } else if (il == DD && g == 0 && jout < DD) {
      if (jout < 80)       v = HMb[jout];
      else if (jout < 100) v = MEb[jout - 80];
      else                 v = TFb[jout - 100];
    }
    Wfrag[a] = f2bf(v);
  }

  for (int a = tid; a < NATT * KP; a += NT) {
    int g = a / KP, n = a - g * KP;
    int i = g * DD + n;
    int col;
    if (i < 800)       col = i % 80;
    else if (i < 1000) col = 80 + (i - 800) % 20;
    else if (i < 1050) col = 100 + (i - 1000) % 5;
    else               col = 100;  // alpha==0 there
    Lut8[a] = (unsigned char)col;
  }
}

// ---------------- main fused kernel ----------------
// 1024 blocks x 256 threads; 4 waves x 32 rows; 2 barriers per group.
// LDS: sCtx 128x112+16 bf16 (28704B) + sAb 28672B + sLut8 1120B = 58496B -> 2 blk/CU.
__global__ __launch_bounds__(256, 2)
void fused_main(const float* __restrict__ hm, const float* __restrict__ me,
                const float* __restrict__ tf,
                const short* __restrict__ Afrag, const short* __restrict__ Wfrag,
                const unsigned char* __restrict__ Lut8,
                float* __restrict__ out, float* __restrict__ alphaOut)
{
  __shared__ __align__(16) short sCtx[RPB * KP + 16];  // +16: c=3 b128 overflow pad
  __shared__ __align__(16) short sAb[FRAG_PER_G * FRAG_ELEMS];
  __shared__ __align__(4)  unsigned char sLut8[NATT * KP];

  const int tid  = threadIdx.x;
  const int lane = tid & 63;
  const int wave = tid >> 6;
  const int l15  = lane & 15;
  const int g16  = lane >> 4;
  const long rowbase = (long)blockIdx.x * RPB;
  const int wrow0 = wave * 32;

  // ---- issue A(0) staging first (7 x 1KB per wave, async) ----
  {
    const short* src = Afrag + (0 * FRAG_PER_G + wave * 7) * FRAG_ELEMS + lane * 8;
    short* dst = &sAb[(wave * 7) * FRAG_ELEMS];
    #pragma unroll
    for (int q = 0; q < 7; ++q)
      gload_lds16(src + q * FRAG_ELEMS, dst + q * FRAG_ELEMS);
  }

  // ---- wave-private ctx staging (rows wrow0..wrow0+31), KP=112 ----
  for (int q = lane; q < 32 * 20; q += 64) {        // hm: 20 f4 per row
    int r = q / 20, c = q - r * 20;
    f4 v = *(const f4*)(hm + (rowbase + wrow0 + r) * 80 + c * 4);
    u32x2 b; b[0] = pkbf(v[0], v[1]); b[1] = pkbf(v[2], v[3]);
    *(u32x2*)&sCtx[(wrow0 + r) * KP + c * 4] = b;
  }
  for (int q = lane; q < 32 * 5; q += 64) {         // me: 5 f4 per row
    int r = q / 5, c = q - r * 5;
    f4 v = *(const f4*)(me + (rowbase + wrow0 + r) * 20 + c * 4);
    u32x2 b; b[0] = pkbf(v[0], v[1]); b[1] = pkbf(v[2], v[3]);
    *(u32x2*)&sCtx[(wrow0 + r) * KP + 80 + c * 4] = b;
  }
  for (int q = lane; q < 32 * 5; q += 64) {         // tf: 5 scalars per row
    int r = q / 5, c = q - r * 5;
    sCtx[(wrow0 + r) * KP + 100 + c] = f2bf(tf[(rowbase + wrow0 + r) * 5 + c]);
  }
  for (int q = lane; q < 32 * 7; q += 64) {         // cols 105..111; col105 = 1.0
    int r = q / 7, c = q - r * 7;
    sCtx[(wrow0 + r) * KP + 105 + c] = (c == 0) ? (short)0x3F80 : (short)0;
  }
  if (lane < 16) sCtx[RPB * KP + lane] = 0;         // overflow pad (all waves, same val)
  for (int q = lane; q < (NATT * KP) / 4; q += 64)  // u8 LUT, redundant identical
    ((unsigned int*)sLut8)[q] = ((const unsigned int*)Lut8)[q];

  // ---- preload ctx MFMA fragments (group-invariant; own rows -> no barrier) ----
  short8v cf0[4], cf1[4];
  #pragma unroll
  for (int c = 0; c < 4; ++c) {
    cf0[c] = *(const short8v*)&sCtx[(wrow0 +      l15) * KP + c * 32 + g16 * 8];
    cf1[c] = *(const short8v*)&sCtx[(wrow0 + 16 + l15) * KP + c * 32 + g16 * 8];
  }

  f4 acc2[2][7];
  #pragma unroll
  for (int rt = 0; rt < 2; ++rt)
    #pragma unroll
    for (int jt = 0; jt < 7; ++jt) {
      acc2[rt][jt][0]=0.f; acc2[rt][jt][1]=0.f; acc2[rt][jt][2]=0.f; acc2[rt][jt][3]=0.f;
    }

  __syncthreads();   // prologue: A(0) landed (implicit vmcnt drain) + ctx/LUT visible

  for (int g = 0; g < NATT; ++g) {
    const short* Wg = Wfrag + g * FRAG_PER_G * FRAG_ELEMS + lane * 8;

    // ---- W cc=0 prefetch (flies across GEMM1+softmax) ----
    short8v wfc[7], wfn[7];
    #pragma unroll
    for (int T = 0; T < 7; ++T) wfc[T] = *(const short8v*)(Wg + T * FRAG_ELEMS);

    // ---- GEMM1 from LDS: z tile D[n][r], n=16T+4*g16+reg, r=l15 ----
    f4 za[2][7];
    #pragma unroll
    for (int T = 0; T < 7; ++T) { za[0][T] = 0.f; za[1][T] = 0.f; }

    #pragma unroll
    for (int c = 0; c < 4; ++c) {
      #pragma unroll
      for (int T = 0; T < 7; ++T) {
        short8v af = *(const short8v*)&sAb[(c * 7 + T) * FRAG_ELEMS + lane * 8];
        za[0][T] = __builtin_amdgcn_mfma_f32_16x16x32_bf16(af, cf0[c], za[0][T], 0, 0, 0);
        za[1][T] = __builtin_amdgcn_mfma_f32_16x16x32_bf16(af, cf1[c], za[1][T], 0, 0, 0);
      }
    }

    __syncthreads();   // #1: A(g) consumed by all waves (drains wfc too - needed anyway)

    // ---- issue A(g+1) staging (async; lands under softmax+GEMM2) ----
    if (g < NATT - 1) {
      const short* src = Afrag + ((g + 1) * FRAG_PER_G + wave * 7) * FRAG_ELEMS + lane * 8;
      short* dst = &sAb[(wave * 7) * FRAG_ELEMS];
      #pragma unroll
      for (int q = 0; q < 7; ++q)
        gload_lds16(src + q * FRAG_ELEMS, dst + q * FRAG_ELEMS);
    }

    // ---- LUT quads (u8x4 per T, shared by both rt) ----
    unsigned int cq[7];
    #pragma unroll
    for (int T = 0; T < 7; ++T)
      cq[T] = *(const unsigned int*)&sLut8[g * KP + T * 16 + g16 * 4];

    // ---- softmax (exp2 of prescaled z, no max-subtract) + alpha + h build ----
    u32x4 hfu[2][4];
    #pragma unroll
    for (int rt = 0; rt < 2; ++rt) {
      float s = 0.f;
      #pragma unroll
      for (int T = 0; T < 7; ++T)
        #pragma unroll
        for (int k = 0; k < 4; ++k) {
          float p = exp2f(za[rt][T][k]);   // pad cols: z=-1.4e30 -> 0
          za[rt][T][k] = p;
          s += p;
        }
      s += __shfl_xor(s, 16);
      s += __shfl_xor(s, 32);
      float inv = __fdividef(1.f, s);

      const int rowl = wrow0 + rt * 16 + l15;
      float* arow = alphaOut + (rowbase + rowl) * 1050 + g * DD;
      const short* crow = &sCtx[rowl * KP];

      #pragma unroll
      for (int T = 0; T < 7; ++T) {
        f4 av = za[rt][T] * inv;
        int n0 = T * 16 + g16 * 4;
        if (T < 6) {
          *(f4u*)(arow + n0) = av;               // dwordx4
        } else {
          if (g16 < 2)       *(f4u*)(arow + n0) = av;
          else if (g16 == 2) arow[104] = av[0];  // n=104 only; n>=105 masked
        }
        float h0 = av[0] * bf2f(crow[(cq[T] >>  0) & 0xFF]);
        float h1 = av[1] * bf2f(crow[(cq[T] >>  8) & 0xFF]);
        float h2 = av[2] * bf2f(crow[(cq[T] >> 16) & 0xFF]);
        float h3 = av[3] * bf2f(crow[(cq[T] >> 24) & 0xFF]);
        hfu[rt][T >> 1][(T & 1) * 2 + 0] = pkbf(h0, h1);
        hfu[rt][T >> 1][(T & 1) * 2 + 1] = pkbf(h2, h3);
      }
      hfu[rt][3][2] = 0u; hfu[rt][3][3] = 0u;    // T=7 half (k-slots unused)
    }
    if (g == 0 && g16 == 2) {      // il=105 slot := 1.0 -> GEMM2 adds out-bias once
      hfu[0][3][0] = (hfu[0][3][0] & 0xFFFFu) | 0x3F800000u;
      hfu[1][3][0] = (hfu[1][3][0] & 0xFFFFu) | 0x3F800000u;
    }

    // ---- GEMM2 accumulate (W register 2-stage pipeline) ----
    #pragma unroll
    for (int cc = 0; cc < 4; ++cc) {
      if (cc < 3) {
        #pragma unroll
        for (int T = 0; T < 7; ++T) wfn[T] = *(const short8v*)(Wg + ((cc + 1) * 7 + T) * FRAG_ELEMS);
      }
      short8v ha0 = __builtin_bit_cast(short8v, hfu[0][cc]);
      short8v ha1 = __builtin_bit_cast(short8v, hfu[1][cc]);
      #pragma unroll
      for (int jt = 0; jt < 7; ++jt) {
        acc2[0][jt] = __builtin_amdgcn_mfma_f32_16x16x32_bf16(ha0, wfc[jt], acc2[0][jt], 0, 0, 0);
        acc2[1][jt] = __builtin_amdgcn_mfma_f32_16x16x32_bf16(ha1, wfc[jt], acc2[1][jt], 0, 0, 0);
      }
      if (cc < 3) {
        #pragma unroll
        for (int T = 0; T < 7; ++T) wfc[T] = wfn[T];
      }
    }

    __syncthreads();   // #2: implicit vmcnt(0) drain -> A(g+1) landed for all waves
  }

  // ---- epilogue: bias already in acc2; D2[r][j]: r=rt*16+4*g16+k, j=16*jt+l15 ----
  #pragma unroll
  for (int jt = 0; jt < 7; ++jt) {
    int j = jt * 16 + l15;
    if (j < DD) {
      #pragma unroll
      for (int rt = 0; rt < 2; ++rt)
        #pragma unroll
        for (int k = 0; k < 4; ++k) {
          long row = rowbase + wrow0 + rt * 16 + g16 * 4 + k;
          out[row * DD + j] = acc2[rt][jt][k];
        }
    }
  }
}

// ---------------- launch ----------------
extern "C" void kernel_launch(void* const* d_in, const int* in_sizes, int n_in,
                              void* d_out, int out_size, void* d_ws, size_t ws_size,
                              hipStream_t stream)
{
  const float* hm  = (const float*)d_in[0];
  const float* me  = (const float*)d_in[1];
  const float* tf  = (const float*)d_in[2];
  const float* Aw  = (const float*)d_in[3];
  const float* Ab  = (const float*)d_in[4];
  const float* HMw = (const float*)d_in[5];
  const float* HMb = (const float*)d_in[6];
  const float* MEw = (const float*)d_in[7];
  const float* MEb = (const float*)d_in[8];
  const float* TFw = (const float*)d_in[9];
  const float* TFb = (const float*)d_in[10];

  char* ws = (char*)d_ws;
  short* Afrag = (short*)(ws + 0);                 // 286720 B
  short* Wfrag = (short*)(ws + 286720);            // 286720 B
  unsigned char* Lut8 = (unsigned char*)(ws + 573440); // 1120 B (total 574560)

  float* outP     = (float*)d_out;
  float* alphaOut = outP + (long)131072 * DD;

  prep_kernel<<<320, 256, 0, stream>>>(Aw, Ab, HMw, HMb, MEw, MEb, TFw, TFb,
                                       Afrag, Wfrag, Lut8);
  fused_main<<<1024, 256, 0, stream>>>(hm, me, tf, Afrag, Wfrag, Lut8,
                                       outP, alphaOut);
}

// Round 7
// 275.153 us; speedup vs baseline: 1.6000x; 1.0553x over previous
//
#include <hip/hip_runtime.h>
#include <stdint.h>

// MultiAttention fused kernel for MI355X (gfx950) — round 7
// B=131072 rows; D=105 (80 hm + 20 me + 5 tf); 10 attention groups.
// out  [B,105] fp32  (first 13,762,560 floats of d_out)
// alpha[B,1050] fp32 (next 137,625,600 floats of d_out)
//
// R7 (vs R6 @290us): 512-thread blocks (8 waves x 16 rows). Same 58.5KB LDS
// -> 2 blocks/CU but now 16 waves/CU (4/SIMD, 2x R6). Single row-tile per
// wave shrinks live state to ~110 VGPR -> fits the 128-reg cap 4 waves/SIMD
// needs (designed-in, unlike R4's spill). A block-shared via global_load_lds
// (per-row traffic unchanged); W per-wave from L2 (2.3GB total, << L2 BW),
// GEMM2 jt-outer so peak W liveness is 8 frags. 2 barriers/group.

#define NATT 10
#define DD   105
#define KP   112          // ctx k pitch (cols 0..104 real, 105=1.0 bias, 106..111=0)
#define RPB  128          // rows per block (8 waves x 16)
#define FRAG_PER_G 28     // c(4) x T(7) fragments per group per operand
#define FRAG_ELEMS 512    // 64 lanes x 8 bf16 (1KB)
#define OP_ELEMS (NATT*FRAG_PER_G*FRAG_ELEMS)

typedef __attribute__((ext_vector_type(8))) short short8v;  // 8 bf16 = MFMA A/B frag
typedef __attribute__((ext_vector_type(4))) float f4;
typedef float f4u __attribute__((ext_vector_type(4), aligned(4)));
typedef __attribute__((ext_vector_type(4))) unsigned int u32x4;
typedef __attribute__((ext_vector_type(2))) unsigned int u32x2;

__device__ __forceinline__ short f2bf(float x) {
  unsigned int u = __builtin_bit_cast(unsigned int, x);
  unsigned int r = (u + 0x7FFFu + ((u >> 16) & 1u)) >> 16;   // RNE
  return (short)(r & 0xFFFFu);
}
__device__ __forceinline__ float bf2f(int b) {
  unsigned int u = ((unsigned int)(b & 0xFFFF)) << 16;
  return __builtin_bit_cast(float, u);
}
__device__ __forceinline__ unsigned int pkbf(float lo, float hi) {
  unsigned int r;
  asm("v_cvt_pk_bf16_f32 %0, %1, %2" : "=v"(r) : "v"(lo), "v"(hi));
  return r;
}
// async global(16B/lane) -> LDS(base + lane*16); fenced by __syncthreads' drain
__device__ __forceinline__ void gload_lds16(const void* g, void* l) {
  __builtin_amdgcn_global_load_lds(
      (const __attribute__((address_space(1))) unsigned int*)g,
      (__attribute__((address_space(3))) unsigned int*)l, 16, 0, 0);
}

// ---------------- prep: build bf16 fragment packs in workspace ----------------
// Afrag[g][c][T][lane][j]: GEMM1 A-operand, PRESCALED by log2(e).
//   n = T*16+(l&15), k = c*32+(l>>4)*8+j
//   k<105: A_w[(g*105+n)*105+k]*L2E (0 if n>=105); k==105: A_b*L2E or -1e30 pad
// Wfrag[g][cc][jt][lane][j]: GEMM2 B-operand, kappa2 k-slot map:
//   il = cc*32 + (l>>4)*4 + (j&3) + 16*(j>>2); jout = jt*16+(l&15)
//   il<105: block-diag [HM|ME|TF] weight; il==105 && g==0: out-bias[jout]
// Lut8 [10][112] u8: expanded-col -> ctx-col map
__global__ void prep_kernel(const float* __restrict__ Aw, const float* __restrict__ Ab,
                            const float* __restrict__ HMw, const float* __restrict__ HMb,
                            const float* __restrict__ MEw, const float* __restrict__ MEb,
                            const float* __restrict__ TFw, const float* __restrict__ TFb,
                            short* __restrict__ Afrag, short* __restrict__ Wfrag,
                            unsigned char* __restrict__ Lut8)
{
  const float L2E = 1.4426950408889634f;
  int tid = blockIdx.x * blockDim.x + threadIdx.x;
  int NT  = gridDim.x * blockDim.x;

  for (int a = tid; a < OP_ELEMS; a += NT) {
    int j = a & 7, l = (a >> 3) & 63;
    int rem = a >> 9;            // g*28 + c*7 + T
    int T = rem % 7, rem2 = rem / 7;
    int c = rem2 & 3, g = rem2 >> 2;
    int n = T * 16 + (l & 15);
    int k = c * 32 + (l >> 4) * 8 + j;
    float v = 0.f;
    if (n < DD && k < DD) v = Aw[(g * DD + n) * DD + k] * L2E;
    else if (k == DD)     v = (n < DD) ? Ab[g * DD + n] * L2E : -1e30f;
    Afrag[a] = f2bf(v);
  }

  for (int a = tid; a < OP_ELEMS; a += NT) {
    int j = a & 7, l = (a >> 3) & 63;
    int rem = a >> 9;
    int jt = rem % 7, rem2 = rem / 7;
    int cc = rem2 & 3, g = rem2 >> 2;
    int jout = jt * 16 + (l & 15);
    int gg = l >> 4;
    int il = cc * 32 + gg * 4 + (j & 3) + ((j >> 2) << 4);
    float v = 0.f;
    if (il < DD && jout < DD) {
      int i = g * DD + il;
      if (i < 800)       { if (jout < 80)                v = HMw[jout * 800 + i]; }
      else if (i < 1000) { if (jout >= 80 && jout < 100) v = MEw[(jout - 80) * 200 + (i - 800)]; }
      else               { if (jout >= 100)              v = TFw[(jout - 100) * 50 + (i - 1000)]; }
    } else if (il == DD && g == 0 && jout < DD) {
      if (jout < 80)       v = HMb[jout];
      else if (jout < 100) v = MEb[jout - 80];
      else                 v = TFb[jout - 100];
    }
    Wfrag[a] = f2bf(v);
  }

  for (int a = tid; a < NATT * KP; a += NT) {
    int g = a / KP, n = a - g * KP;
    int i = g * DD + n;
    int col;
    if (i < 800)       col = i % 80;
    else if (i < 1000) col = 80 + (i - 800) % 20;
    else if (i < 1050) col = 100 + (i - 1000) % 5;
    else               col = 100;  // alpha==0 there
    Lut8[a] = (unsigned char)col;
  }
}

// ---------------- main fused kernel ----------------
// 1024 blocks x 512 threads; 8 waves x 16 rows; 2 barriers per group.
// LDS: sCtx 128x112+16 bf16 (28704B) + sAb 28672B + sLut8 1120B = 58496B.
// 2 blocks/CU (LDS) x 8 waves = 16 waves/CU = 4/SIMD -> 128-VGPR cap.
__global__ __launch_bounds__(512, 4)
void fused_main(const float* __restrict__ hm, const float* __restrict__ me,
                const float* __restrict__ tf,
                const short* __restrict__ Afrag, const short* __restrict__ Wfrag,
                const unsigned char* __restrict__ Lut8,
                float* __restrict__ out, float* __restrict__ alphaOut)
{
  __shared__ __align__(16) short sCtx[RPB * KP + 16];  // +16: c=3 b128 overflow pad
  __shared__ __align__(16) short sAb[FRAG_PER_G * FRAG_ELEMS];
  __shared__ __align__(4)  unsigned char sLut8[NATT * KP];

  const int tid  = threadIdx.x;
  const int lane = tid & 63;
  const int wave = tid >> 6;          // 0..7
  const int l15  = lane & 15;
  const int g16  = lane >> 4;
  const long rowbase = (long)blockIdx.x * RPB;
  const int wrow0 = wave * 16;        // this wave's first local row

  // ---- issue A(0) staging first (28 frags split across 8 waves, async) ----
  for (int q = wave; q < FRAG_PER_G; q += 8)
    gload_lds16(Afrag + q * FRAG_ELEMS + lane * 8, &sAb[q * FRAG_ELEMS]);

  // ---- wave-private ctx staging (rows wrow0..wrow0+15), KP=112 ----
  for (int q = lane; q < 16 * 20; q += 64) {        // hm: 20 f4 per row
    int r = q / 20, c = q - r * 20;
    f4 v = *(const f4*)(hm + (rowbase + wrow0 + r) * 80 + c * 4);
    u32x2 b; b[0] = pkbf(v[0], v[1]); b[1] = pkbf(v[2], v[3]);
    *(u32x2*)&sCtx[(wrow0 + r) * KP + c * 4] = b;
  }
  for (int q = lane; q < 16 * 5; q += 64) {         // me: 5 f4 per row
    int r = q / 5, c = q - r * 5;
    f4 v = *(const f4*)(me + (rowbase + wrow0 + r) * 20 + c * 4);
    u32x2 b; b[0] = pkbf(v[0], v[1]); b[1] = pkbf(v[2], v[3]);
    *(u32x2*)&sCtx[(wrow0 + r) * KP + 80 + c * 4] = b;
  }
  for (int q = lane; q < 16 * 5; q += 64) {         // tf: 5 scalars per row
    int r = q / 5, c = q - r * 5;
    sCtx[(wrow0 + r) * KP + 100 + c] = f2bf(tf[(rowbase + wrow0 + r) * 5 + c]);
  }
  for (int q = lane; q < 16 * 7; q += 64) {         // cols 105..111; col105 = 1.0
    int r = q / 7, c = q - r * 7;
    sCtx[(wrow0 + r) * KP + 105 + c] = (c == 0) ? (short)0x3F80 : (short)0;
  }
  if (tid < 16) sCtx[RPB * KP + tid] = 0;           // overflow pad
  for (int q = tid; q < (NATT * KP) / 4; q += 512)  // u8 LUT
    ((unsigned int*)sLut8)[q] = ((const unsigned int*)Lut8)[q];

  f4 acc2[7];
  #pragma unroll
  for (int jt = 0; jt < 7; ++jt) {
    acc2[jt][0]=0.f; acc2[jt][1]=0.f; acc2[jt][2]=0.f; acc2[jt][3]=0.f;
  }

  __syncthreads();   // prologue: A(0) landed (implicit vmcnt drain) + ctx/LUT visible

  for (int g = 0; g < NATT; ++g) {
    const short* Wg = Wfrag + g * FRAG_PER_G * FRAG_ELEMS + lane * 8;

    // ---- GEMM1 from LDS: z tile D[n][r], n=16T+4*g16+reg, r=l15 ----
    f4 za[7];
    #pragma unroll
    for (int T = 0; T < 7; ++T) { za[T][0]=0.f; za[T][1]=0.f; za[T][2]=0.f; za[T][3]=0.f; }

    #pragma unroll
    for (int c = 0; c < 4; ++c) {
      short8v cf = *(const short8v*)&sCtx[(wrow0 + l15) * KP + c * 32 + g16 * 8];
      #pragma unroll
      for (int T = 0; T < 7; ++T) {
        short8v af = *(const short8v*)&sAb[(c * 7 + T) * FRAG_ELEMS + lane * 8];
        za[T] = __builtin_amdgcn_mfma_f32_16x16x32_bf16(af, cf, za[T], 0, 0, 0);
      }
    }

    __syncthreads();   // #1: A(g) consumed by all waves

    // ---- issue A(g+1) staging (async; lands under softmax+GEMM2) ----
    if (g < NATT - 1) {
      const short* src = Afrag + (g + 1) * FRAG_PER_G * FRAG_ELEMS + lane * 8;
      for (int q = wave; q < FRAG_PER_G; q += 8)
        gload_lds16(src + q * FRAG_ELEMS, &sAb[q * FRAG_ELEMS]);
    }

    // ---- LUT quads (u8x4 per T) ----
    unsigned int cq[7];
    #pragma unroll
    for (int T = 0; T < 7; ++T)
      cq[T] = *(const unsigned int*)&sLut8[g * KP + T * 16 + g16 * 4];

    // ---- softmax (exp2 of prescaled z, no max-subtract) ----
    float s = 0.f;
    #pragma unroll
    for (int T = 0; T < 7; ++T)
      #pragma unroll
      for (int k = 0; k < 4; ++k) {
        float p = exp2f(za[T][k]);   // pad cols: z=-1.4e30 -> 0
        za[T][k] = p;
        s += p;
      }
    s += __shfl_xor(s, 16);
    s += __shfl_xor(s, 32);
    float inv = __fdividef(1.f, s);

    const int rowl = wrow0 + l15;
    float* arow = alphaOut + (rowbase + rowl) * 1050 + g * DD;
    const short* crow = &sCtx[rowl * KP];

    // ---- alpha store + h build ----
    u32x4 hfu[4];
    #pragma unroll
    for (int T = 0; T < 7; ++T) {
      f4 av = za[T] * inv;
      int n0 = T * 16 + g16 * 4;
      if (T < 6) {
        *(f4u*)(arow + n0) = av;               // dwordx4
      } else {
        if (g16 < 2)       *(f4u*)(arow + n0) = av;
        else if (g16 == 2) arow[104] = av[0];  // n=104 only; n>=105 masked
      }
      float h0 = av[0] * bf2f(crow[(cq[T] >>  0) & 0xFF]);
      float h1 = av[1] * bf2f(crow[(cq[T] >>  8) & 0xFF]);
      float h2 = av[2] * bf2f(crow[(cq[T] >> 16) & 0xFF]);
      float h3 = av[3] * bf2f(crow[(cq[T] >> 24) & 0xFF]);
      hfu[T >> 1][(T & 1) * 2 + 0] = pkbf(h0, h1);
      hfu[T >> 1][(T & 1) * 2 + 1] = pkbf(h2, h3);
    }
    hfu[3][2] = 0u; hfu[3][3] = 0u;            // T=7 half (k-slots unused)
    if (g == 0 && g16 == 2) {      // il=105 slot := 1.0 -> GEMM2 adds out-bias once
      hfu[3][0] = (hfu[3][0] & 0xFFFFu) | 0x3F800000u;
    }

    // ---- GEMM2 accumulate: jt-outer, cc-inner (<=8 W frags live) ----
    short8v ha0 = __builtin_bit_cast(short8v, hfu[0]);
    short8v ha1 = __builtin_bit_cast(short8v, hfu[1]);
    short8v ha2 = __builtin_bit_cast(short8v, hfu[2]);
    short8v ha3 = __builtin_bit_cast(short8v, hfu[3]);
    #pragma unroll
    for (int jt = 0; jt < 7; ++jt) {
      short8v w0 = *(const short8v*)(Wg + (0 * 7 + jt) * FRAG_ELEMS);
      short8v w1 = *(const short8v*)(Wg + (1 * 7 + jt) * FRAG_ELEMS);
      short8v w2 = *(const short8v*)(Wg + (2 * 7 + jt) * FRAG_ELEMS);
      short8v w3 = *(const short8v*)(Wg + (3 * 7 + jt) * FRAG_ELEMS);
      f4 a = acc2[jt];
      a = __builtin_amdgcn_mfma_f32_16x16x32_bf16(ha0, w0, a, 0, 0, 0);
      a = __builtin_amdgcn_mfma_f32_16x16x32_bf16(ha1, w1, a, 0, 0, 0);
      a = __builtin_amdgcn_mfma_f32_16x16x32_bf16(ha2, w2, a, 0, 0, 0);
      a = __builtin_amdgcn_mfma_f32_16x16x32_bf16(ha3, w3, a, 0, 0, 0);
      acc2[jt] = a;
    }

    __syncthreads();   // #2: implicit vmcnt(0) drain -> A(g+1) landed for all waves
  }

  // ---- epilogue: bias already in acc2; D2[r][j]: r=4*g16+k, j=16*jt+l15 ----
  #pragma unroll
  for (int jt = 0; jt < 7; ++jt) {
    int j = jt * 16 + l15;
    if (j < DD) {
      #pragma unroll
      for (int k = 0; k < 4; ++k) {
        long row = rowbase + wrow0 + g16 * 4 + k;
        out[row * DD + j] = acc2[jt][k];
      }
    }
  }
}

// ---------------- launch ----------------
extern "C" void kernel_launch(void* const* d_in, const int* in_sizes, int n_in,
                              void* d_out, int out_size, void* d_ws, size_t ws_size,
                              hipStream_t stream)
{
  const float* hm  = (const float*)d_in[0];
  const float* me  = (const float*)d_in[1];
  const float* tf  = (const float*)d_in[2];
  const float* Aw  = (const float*)d_in[3];
  const float* Ab  = (const float*)d_in[4];
  const float* HMw = (const float*)d_in[5];
  const float* HMb = (const float*)d_in[6];
  const float* MEw = (const float*)d_in[7];
  const float* MEb = (const float*)d_in[8];
  const float* TFw = (const float*)d_in[9];
  const float* TFb = (const float*)d_in[10];

  char* ws = (char*)d_ws;
  short* Afrag = (short*)(ws + 0);                 // 286720 B
  short* Wfrag = (short*)(ws + 286720);            // 286720 B
  unsigned char* Lut8 = (unsigned char*)(ws + 573440); // 1120 B (total 574560)

  float* outP     = (float*)d_out;
  float* alphaOut = outP + (long)131072 * DD;

  prep_kernel<<<320, 256, 0, stream>>>(Aw, Ab, HMw, HMb, MEw, MEb, TFw, TFb,
                                       Afrag, Wfrag, Lut8);
  fused_main<<<1024, 512, 0, stream>>>(hm, me, tf, Afrag, Wfrag, Lut8,
                                       outP, alphaOut);
}

// Round 8
// 239.688 us; speedup vs baseline: 1.8368x; 1.1480x over previous
//
#include <hip/hip_runtime.h>
#include <stdint.h>

// MultiAttention fused kernel for MI355X (gfx950) — round 8
// B=131072 rows; D=105 (80 hm + 20 me + 5 tf); 10 attention groups.
// out  [B,105] fp32; alpha [B,1050] fp32 (d_out = [out | alpha]).
//
// R8 (vs R7 @275us): W fragments ALSO staged in block-shared LDS (traffic /8,
// GEMM2 L2 loads -> ds_read_b128). To fit 2 blocks/CU, K trimmed 128->112:
// 4th K-chunk is a HALF fragment (real k=96..111 packed into MFMA k-slots
// {gg*8+j, j<4} on BOTH operands; A-side upper 4 slots zeroed in regs).
// Schedule (2 barriers/group): B1 after GEMM1 -> stage A(g+1) (covered by
// softmax+GEMM2); B2 after GEMM2 -> stage W(g+1) (covered by next GEMM1).
// LDS: ctx 28672 + A 25600 + W 25600 + lut 1120 = 80992B -> 2 blk/CU,
// 16 waves/CU at 128-VGPR cap (512 threads, launch_bounds(512,4)).

#define NATT 10
#define DD   105
#define KP   112          // ctx k pitch (0..104 real, 105=1.0 bias, 106..111=0)
#define RPB  128          // rows per block (8 waves x 16)
#define SLAB 12800        // shorts per operand group slab (25600 B = 25 chunks)
#define HOFF 10752        // shorts: offset of half-frag region (21 full KB)
#define FRAG_ELEMS 512    // full frag: 64 lanes x 8 bf16 (1KB)

typedef __attribute__((ext_vector_type(8))) short short8v;
typedef __attribute__((ext_vector_type(4))) short short4v;
typedef __attribute__((ext_vector_type(4))) float f4;
typedef float f4u __attribute__((ext_vector_type(4), aligned(4)));
typedef __attribute__((ext_vector_type(4))) unsigned int u32x4;
typedef __attribute__((ext_vector_type(2))) unsigned int u32x2;

__device__ __forceinline__ short f2bf(float x) {
  unsigned int u = __builtin_bit_cast(unsigned int, x);
  unsigned int r = (u + 0x7FFFu + ((u >> 16) & 1u)) >> 16;   // RNE
  return (short)(r & 0xFFFFu);
}
__device__ __forceinline__ float bf2f(int b) {
  unsigned int u = ((unsigned int)(b & 0xFFFF)) << 16;
  return __builtin_bit_cast(float, u);
}
__device__ __forceinline__ unsigned int pkbf(float lo, float hi) {
  unsigned int r;
  asm("v_cvt_pk_bf16_f32 %0, %1, %2" : "=v"(r) : "v"(lo), "v"(hi));
  return r;
}
__device__ __forceinline__ void gload_lds16(const void* g, void* l) {
  __builtin_amdgcn_global_load_lds(
      (const __attribute__((address_space(1))) unsigned int*)g,
      (__attribute__((address_space(3))) unsigned int*)l, 16, 0, 0);
}

// ---------------- prep: build bf16 fragment packs ----------------
// A slab [g]: full (c<3,T): (c*7+T)*512 sh; lane l elem j: n=T*16+(l&15),
//   k=c*32+(l>>4)*8+j (<=95), v=Aw[g*105+n][k]*L2E (0 if n>=105).
//   half (T): HOFF+T*256 sh; elem j<4: kk=96+(l>>4)*4+j;
//   kk<105: Aw*L2E; kk==105: Ab*L2E (n<105) else -1e30; kk>105: 0.
// W slab [g]: full (cc<3,jt): jout=jt*16+(l&15); il=cc*32+gg*4+(j&3)+16*(j>>2);
//   half (jt): il=96+gg*4+j (j<4); il==105&&g==0 -> out-bias[jout].
// Lut8 [10][112] u8: expanded-col -> ctx-col.
__device__ __forceinline__ float wblockdiag(int jout, int i,
    const float* HMw, const float* MEw, const float* TFw) {
  float v = 0.f;
  if (i < 800)       { if (jout < 80)                v = HMw[jout * 800 + i]; }
  else if (i < 1000) { if (jout >= 80 && jout < 100) v = MEw[(jout - 80) * 200 + (i - 800)]; }
  else               { if (jout >= 100)              v = TFw[(jout - 100) * 50 + (i - 1000)]; }
  return v;
}

__global__ void prep_kernel(const float* __restrict__ Aw, const float* __restrict__ Ab,
                            const float* __restrict__ HMw, const float* __restrict__ HMb,
                            const float* __restrict__ MEw, const float* __restrict__ MEb,
                            const float* __restrict__ TFw, const float* __restrict__ TFb,
                            short* __restrict__ Afrag, short* __restrict__ Wfrag,
                            unsigned char* __restrict__ Lut8)
{
  const float L2E = 1.4426950408889634f;
  int tid = blockIdx.x * blockDim.x + threadIdx.x;
  int NT  = gridDim.x * blockDim.x;

  // A full frags
  for (int a = tid; a < NATT * 21 * 512; a += NT) {
    int j = a & 7, l = (a >> 3) & 63;
    int fi = (a >> 9) % 21, g = (a >> 9) / 21;
    int c = fi / 7, T = fi % 7;
    int n = T * 16 + (l & 15);
    int k = c * 32 + (l >> 4) * 8 + j;
    float v = (n < DD) ? Aw[(g * DD + n) * DD + k] * L2E : 0.f;
    Afrag[g * SLAB + fi * 512 + l * 8 + j] = f2bf(v);
  }
  // A half frags
  for (int a = tid; a < NATT * 7 * 256; a += NT) {
    int j = a & 3, l = (a >> 2) & 63;
    int T = (a >> 8) % 7, g = (a >> 8) / 7;
    int n = T * 16 + (l & 15);
    int kk = 96 + (l >> 4) * 4 + j;
    float v;
    if (kk < DD)       v = (n < DD) ? Aw[(g * DD + n) * DD + kk] * L2E : 0.f;
    else if (kk == DD) v = (n < DD) ? Ab[g * DD + n] * L2E : -1e30f;
    else               v = 0.f;
    Afrag[g * SLAB + HOFF + T * 256 + l * 4 + j] = f2bf(v);
  }
  // A pad tail per slab
  for (int a = tid; a < NATT * 256; a += NT)
    Afrag[(a >> 8) * SLAB + 12544 + (a & 255)] = 0;

  // W full frags
  for (int a = tid; a < NATT * 21 * 512; a += NT) {
    int j = a & 7, l = (a >> 3) & 63;
    int fi = (a >> 9) % 21, g = (a >> 9) / 21;
    int cc = fi / 7, jt = fi % 7;
    int jout = jt * 16 + (l & 15);
    int gg = l >> 4;
    int il = cc * 32 + gg * 4 + (j & 3) + ((j >> 2) << 4);   // <= 95
    float v = (jout < DD) ? wblockdiag(jout, g * DD + il, HMw, MEw, TFw) : 0.f;
    Wfrag[g * SLAB + fi * 512 + l * 8 + j] = f2bf(v);
  }
  // W half frags
  for (int a = tid; a < NATT * 7 * 256; a += NT) {
    int j = a & 3, l = (a >> 2) & 63;
    int jt = (a >> 8) % 7, g = (a >> 8) / 7;
    int jout = jt * 16 + (l & 15);
    int gg = l >> 4;
    int il = 96 + gg * 4 + j;
    float v = 0.f;
    if (il < DD && jout < DD) v = wblockdiag(jout, g * DD + il, HMw, MEw, TFw);
    else if (il == DD && g == 0 && jout < DD) {
      if (jout < 80)       v = HMb[jout];
      else if (jout < 100) v = MEb[jout - 80];
      else                 v = TFb[jout - 100];
    }
    Wfrag[g * SLAB + HOFF + jt * 256 + l * 4 + j] = f2bf(v);
  }
  // W pad tail
  for (int a = tid; a < NATT * 256; a += NT)
    Wfrag[(a >> 8) * SLAB + 12544 + (a & 255)] = 0;

  for (int a = tid; a < NATT * KP; a += NT) {
    int g = a / KP, n = a - g * KP;
    int i = g * DD + n;
    int col;
    if (i < 800)       col = i % 80;
    else if (i < 1000) col = 80 + (i - 800) % 20;
    else if (i < 1050) col = 100 + (i - 1000) % 5;
    else               col = 100;  // alpha==0 there
    Lut8[a] = (unsigned char)col;
  }
}

// ---------------- main fused kernel ----------------
__global__ __launch_bounds__(512, 4)
void fused_main(const float* __restrict__ hm, const float* __restrict__ me,
                const float* __restrict__ tf,
                const short* __restrict__ Afrag, const short* __restrict__ Wfrag,
                const unsigned char* __restrict__ Lut8,
                float* __restrict__ out, float* __restrict__ alphaOut)
{
  __shared__ __align__(16) short sCtx[RPB * KP];        // 28672 B
  __shared__ __align__(16) short sAb[SLAB];             // 25600 B
  __shared__ __align__(16) short sWb[SLAB];             // 25600 B
  __shared__ __align__(4)  unsigned char sLut8[NATT * KP]; // 1120 B

  const int tid  = threadIdx.x;
  const int lane = tid & 63;
  const int wave = tid >> 6;          // 0..7
  const int l15  = lane & 15;
  const int g16  = lane >> 4;
  const long rowbase = (long)blockIdx.x * RPB;
  const int wrow0 = wave * 16;

  // ---- issue A(0), W(0) staging (25 chunks each, split across 8 waves) ----
  #pragma unroll
  for (int q = 0; q < 4; ++q) {
    int ch = q * 8 + wave;
    if (ch < 25) {
      gload_lds16(Afrag + ch * 512 + lane * 8, sAb + ch * 512 + lane * 8);
      gload_lds16(Wfrag + ch * 512 + lane * 8, sWb + ch * 512 + lane * 8);
    }
  }

  // ---- wave-private ctx staging (rows wrow0..wrow0+15), KP=112 ----
  for (int q = lane; q < 16 * 20; q += 64) {        // hm: 20 f4 per row
    int r = q / 20, c = q - r * 20;
    f4 v = *(const f4*)(hm + (rowbase + wrow0 + r) * 80 + c * 4);
    u32x2 b; b[0] = pkbf(v[0], v[1]); b[1] = pkbf(v[2], v[3]);
    *(u32x2*)&sCtx[(wrow0 + r) * KP + c * 4] = b;
  }
  for (int q = lane; q < 16 * 5; q += 64) {         // me: 5 f4 per row
    int r = q / 5, c = q - r * 5;
    f4 v = *(const f4*)(me + (rowbase + wrow0 + r) * 20 + c * 4);
    u32x2 b; b[0] = pkbf(v[0], v[1]); b[1] = pkbf(v[2], v[3]);
    *(u32x2*)&sCtx[(wrow0 + r) * KP + 80 + c * 4] = b;
  }
  for (int q = lane; q < 16 * 5; q += 64) {         // tf: 5 scalars per row
    int r = q / 5, c = q - r * 5;
    sCtx[(wrow0 + r) * KP + 100 + c] = f2bf(tf[(rowbase + wrow0 + r) * 5 + c]);
  }
  for (int q = lane; q < 16 * 7; q += 64) {         // cols 105..111; col105 = 1.0
    int r = q / 7, c = q - r * 7;
    sCtx[(wrow0 + r) * KP + 105 + c] = (c == 0) ? (short)0x3F80 : (short)0;
  }
  for (int q = tid; q < (NATT * KP) / 4; q += 512)  // u8 LUT
    ((unsigned int*)sLut8)[q] = ((const unsigned int*)Lut8)[q];

  // ---- preload ctx MFMA fragments (group-invariant, wave-private rows) ----
  short8v cf[3];
  #pragma unroll
  for (int c = 0; c < 3; ++c)
    cf[c] = *(const short8v*)&sCtx[(wrow0 + l15) * KP + c * 32 + g16 * 8];
  short8v cf3x;
  {
    short4v c4 = *(const short4v*)&sCtx[(wrow0 + l15) * KP + 96 + g16 * 4];
    cf3x = short8v{c4[0], c4[1], c4[2], c4[3], 0, 0, 0, 0};
  }

  f4 acc2[7];
  #pragma unroll
  for (int jt = 0; jt < 7; ++jt) {
    acc2[jt][0]=0.f; acc2[jt][1]=0.f; acc2[jt][2]=0.f; acc2[jt][3]=0.f;
  }

  __syncthreads();   // prologue: A(0),W(0) landed + ctx/LUT visible

  for (int g = 0; g < NATT; ++g) {
    // ---- GEMM1: z tile D[n][r], n=16T+4*g16+reg, r=l15; K=112 ----
    f4 za[7];
    #pragma unroll
    for (int T = 0; T < 7; ++T) { za[T][0]=0.f; za[T][1]=0.f; za[T][2]=0.f; za[T][3]=0.f; }

    #pragma unroll
    for (int c = 0; c < 3; ++c) {
      #pragma unroll
      for (int T = 0; T < 7; ++T) {
        short8v af = *(const short8v*)&sAb[(c * 7 + T) * FRAG_ELEMS + lane * 8];
        za[T] = __builtin_amdgcn_mfma_f32_16x16x32_bf16(af, cf[c], za[T], 0, 0, 0);
      }
    }
    #pragma unroll
    for (int T = 0; T < 7; ++T) {                     // half chunk k=96..111
      short4v a4 = *(const short4v*)&sAb[HOFF + T * 256 + lane * 4];
      short8v af3 = short8v{a4[0], a4[1], a4[2], a4[3], 0, 0, 0, 0};
      za[T] = __builtin_amdgcn_mfma_f32_16x16x32_bf16(af3, cf3x, za[T], 0, 0, 0);
    }

    __syncthreads();   // B1: sA(g) consumed by all (drain: old stores only)

    // ---- stage A(g+1) (lands before B2's drain, covered by softmax+GEMM2) ----
    if (g < NATT - 1) {
      const short* src = Afrag + (g + 1) * SLAB;
      #pragma unroll
      for (int q = 0; q < 4; ++q) {
        int ch = q * 8 + wave;
        if (ch < 25) gload_lds16(src + ch * 512 + lane * 8, sAb + ch * 512 + lane * 8);
      }
    }

    // ---- LUT quads ----
    unsigned int cq[7];
    #pragma unroll
    for (int T = 0; T < 7; ++T)
      cq[T] = *(const unsigned int*)&sLut8[g * KP + T * 16 + g16 * 4];

    // ---- softmax (exp2 of prescaled z, no max-subtract) ----
    float s = 0.f;
    #pragma unroll
    for (int T = 0; T < 7; ++T)
      #pragma unroll
      for (int k = 0; k < 4; ++k) {
        float p = exp2f(za[T][k]);
        za[T][k] = p;
        s += p;
      }
    s += __shfl_xor(s, 16);
    s += __shfl_xor(s, 32);
    float inv = __fdividef(1.f, s);

    const int rowl = wrow0 + l15;
    float* arow = alphaOut + (rowbase + rowl) * 1050 + g * DD;
    const short* crow = &sCtx[rowl * KP];

    // ---- alpha store + h build ----
    u32x4 hfu[4];
    #pragma unroll
    for (int T = 0; T < 7; ++T) {
      f4 av = za[T] * inv;
      int n0 = T * 16 + g16 * 4;
      if (T < 6) {
        *(f4u*)(arow + n0) = av;
      } else {
        if (g16 < 2)       *(f4u*)(arow + n0) = av;
        else if (g16 == 2) arow[104] = av[0];
      }
      float h0 = av[0] * bf2f(crow[(cq[T] >>  0) & 0xFF]);
      float h1 = av[1] * bf2f(crow[(cq[T] >>  8) & 0xFF]);
      float h2 = av[2] * bf2f(crow[(cq[T] >> 16) & 0xFF]);
      float h3 = av[3] * bf2f(crow[(cq[T] >> 24) & 0xFF]);
      hfu[T >> 1][(T & 1) * 2 + 0] = pkbf(h0, h1);
      hfu[T >> 1][(T & 1) * 2 + 1] = pkbf(h2, h3);
    }
    hfu[3][2] = 0u; hfu[3][3] = 0u;                 // cc=3 upper slots = 0
    if (g == 0 && g16 == 2) {                       // il=105 slot := 1.0 (out-bias)
      hfu[3][0] = (hfu[3][0] & 0xFFFFu) | 0x3F800000u;
    }

    // ---- GEMM2 from LDS: jt-outer; 3 full + 1 half chunk per jt ----
    short8v ha0 = __builtin_bit_cast(short8v, hfu[0]);
    short8v ha1 = __builtin_bit_cast(short8v, hfu[1]);
    short8v ha2 = __builtin_bit_cast(short8v, hfu[2]);
    short8v ha3 = __builtin_bit_cast(short8v, hfu[3]);
    #pragma unroll
    for (int jt = 0; jt < 7; ++jt) {
      short8v w0 = *(const short8v*)&sWb[(0 * 7 + jt) * FRAG_ELEMS + lane * 8];
      short8v w1 = *(const short8v*)&sWb[(1 * 7 + jt) * FRAG_ELEMS + lane * 8];
      short8v w2 = *(const short8v*)&sWb[(2 * 7 + jt) * FRAG_ELEMS + lane * 8];
      short4v w3h = *(const short4v*)&sWb[HOFF + jt * 256 + lane * 4];
      short8v w3 = short8v{w3h[0], w3h[1], w3h[2], w3h[3], 0, 0, 0, 0};
      f4 a = acc2[jt];
      a = __builtin_amdgcn_mfma_f32_16x16x32_bf16(ha0, w0, a, 0, 0, 0);
      a = __builtin_amdgcn_mfma_f32_16x16x32_bf16(ha1, w1, a, 0, 0, 0);
      a = __builtin_amdgcn_mfma_f32_16x16x32_bf16(ha2, w2, a, 0, 0, 0);
      a = __builtin_amdgcn_mfma_f32_16x16x32_bf16(ha3, w3, a, 0, 0, 0);
      acc2[jt] = a;
    }

    __syncthreads();   // B2: sW(g) consumed by all; drain -> A(g+1) landed

    // ---- stage W(g+1) (covered by next GEMM1 until B1's drain) ----
    if (g < NATT - 1) {
      const short* src = Wfrag + (g + 1) * SLAB;
      #pragma unroll
      for (int q = 0; q < 4; ++q) {
        int ch = q * 8 + wave;
        if (ch < 25) gload_lds16(src + ch * 512 + lane * 8, sWb + ch * 512 + lane * 8);
      }
    }
  }

  // ---- epilogue: bias already in acc2; D2[r][j]: r=4*g16+k, j=16*jt+l15 ----
  #pragma unroll
  for (int jt = 0; jt < 7; ++jt) {
    int j = jt * 16 + l15;
    if (j < DD) {
      #pragma unroll
      for (int k = 0; k < 4; ++k) {
        long row = rowbase + wrow0 + g16 * 4 + k;
        out[row * DD + j] = acc2[jt][k];
      }
    }
  }
}

// ---------------- launch ----------------
extern "C" void kernel_launch(void* const* d_in, const int* in_sizes, int n_in,
                              void* d_out, int out_size, void* d_ws, size_t ws_size,
                              hipStream_t stream)
{
  const float* hm  = (const float*)d_in[0];
  const float* me  = (const float*)d_in[1];
  const float* tf  = (const float*)d_in[2];
  const float* Aw  = (const float*)d_in[3];
  const float* Ab  = (const float*)d_in[4];
  const float* HMw = (const float*)d_in[5];
  const float* HMb = (const float*)d_in[6];
  const float* MEw = (const float*)d_in[7];
  const float* MEb = (const float*)d_in[8];
  const float* TFw = (const float*)d_in[9];
  const float* TFb = (const float*)d_in[10];

  char* ws = (char*)d_ws;
  short* Afrag = (short*)(ws + 0);                 // 256000 B
  short* Wfrag = (short*)(ws + 256000);            // 256000 B
  unsigned char* Lut8 = (unsigned char*)(ws + 512000); // 1120 B (total 513120)

  float* outP     = (float*)d_out;
  float* alphaOut = outP + (long)131072 * DD;

  prep_kernel<<<320, 256, 0, stream>>>(Aw, Ab, HMw, HMb, MEw, MEb, TFw, TFb,
                                       Afrag, Wfrag, Lut8);
  fused_main<<<1024, 512, 0, stream>>>(hm, me, tf, Afrag, Wfrag, Lut8,
                                       outP, alphaOut);
}